// Round 4
// baseline (582.854 us; speedup 1.0000x reference)
//
#include <hip/hip_runtime.h>

// ---------------------------------------------------------------------------
// B=4, S=4096, D=1024 linear attention (phi = elu+1), bf16 MFMA GEMMs.
// R4: algebra: out = z*(q @ (k_phi^T (v@Wo))) with Wvo = Wv@Wo prefolded
//     (kills the kv@Wo GEMM on the hot chain); one mega 3-head projection
//     GEMM (k/v''/q, N=3072) with fused ksum atomics; merged cvts.
// ---------------------------------------------------------------------------

typedef __bf16 bf16x8 __attribute__((ext_vector_type(8)));
typedef __bf16 bf16x4 __attribute__((ext_vector_type(4)));
typedef float  f32x4  __attribute__((ext_vector_type(4)));

#define GLOBAL_AS __attribute__((address_space(1)))
#define LDS_AS    __attribute__((address_space(3)))

#define SS 4096
#define DD 1024

__device__ __forceinline__ __bf16 f2bf(float f) {
  union { float f; unsigned u; } a; a.f = f;
  unsigned r = a.u + 0x7FFFu + ((a.u >> 16) & 1u);   // RNE (no NaN inputs here)
  union { unsigned short s; __bf16 b; } o; o.s = (unsigned short)(r >> 16);
  return o.b;
}

__device__ __forceinline__ void async_load16(const void* g, void* l) {
  __builtin_amdgcn_global_load_lds((const GLOBAL_AS void*)g, (LDS_AS void*)l, 16, 0, 0);
}

// ---------------------------------------------------------------------------
// Generic BT-GEMM: C[m][n] = sum_k A[m][k] * BT[n][k]
// 128x128 tile, BK=64, 4 waves (2x2), XOR-swizzled LDS (conflict-free b128).
// MODE: 5 = split-K(4) fp32 atomicAdd partials (M2T = v''^T k_phi)
//       7 = plain->bf16 (WvoT = Wo^T @ Wv^T)
//       8 = z*acc + bias + residual -> f32 (final; B operand per-batch)
// ---------------------------------------------------------------------------
template<int MODE>
__global__ __launch_bounds__(256)
void gemm_bt(const __bf16* __restrict__ Ag, const __bf16* __restrict__ Bg,
             void* __restrict__ Cg,
             int N, int K, long sA, long sB, long sC,
             const float* __restrict__ bias,
             const float* __restrict__ zvec,
             const float* __restrict__ resid)
{
  __shared__ __bf16 As[128 * 64];
  __shared__ __bf16 Bs[128 * 64];

  // XCD-aware swizzle (linear id % 8 = XCD): XCD j owns a contiguous band of
  // row-panels, sweeping all bx of one by before advancing.
  int bx = blockIdx.x, by = blockIdx.y;
  {
    const int gx = gridDim.x, gy = gridDim.y;
    if ((gy & 7) == 0) {
      const int f = by * gx + bx;
      const int j = f & 7;
      const int u = f >> 3;
      bx = u % gx;
      by = j * (gy >> 3) + u / gx;
    }
  }
  int bz = blockIdx.z;
  int k0beg = 0, k0end = K;
  if (MODE == 5) {               // z = batch*4 + split
    const int split = bz & 3;
    bz >>= 2;
    k0beg = split * (K >> 2);
    k0end = k0beg + (K >> 2);
  }

  const int tid = threadIdx.x;
  const long m0 = (long)by * 128;
  const __bf16* A = Ag + m0 * K + bz * sA;
  const __bf16* B;
  if (MODE == 8) {
    const int b = (int)(m0 >> 12);           // batch = m0 / S
    B = Bg + (long)bx * 128 * K + (long)b * sB;
  } else {
    B = Bg + (long)bx * 128 * K + bz * sB;
  }

  const int srow = tid >> 3;                      // 0..31
  const int gcc8 = ((tid & 7) ^ (srow & 7)) * 8;  // XOR-swizzled global chunk

  const int lane = tid & 63;
  const int wave = tid >> 6;
  const int wm   = (wave >> 1) * 64;
  const int wn   = (wave & 1) * 64;
  const int ln   = lane & 15;
  const int quad = lane >> 4;
  const int rk   = ln & 7;

  f32x4 acc[4][4];
  const f32x4 zero = {0.f, 0.f, 0.f, 0.f};
#pragma unroll
  for (int i = 0; i < 4; i++)
#pragma unroll
    for (int j = 0; j < 4; j++) acc[i][j] = zero;

  for (int k0 = k0beg; k0 < k0end; k0 += 64) {
#pragma unroll
    for (int p = 0; p < 4; p++) {
      async_load16(A + (long)(p * 32 + srow) * K + k0 + gcc8, As + p * 2048 + tid * 8);
      async_load16(B + (long)(p * 32 + srow) * K + k0 + gcc8, Bs + p * 2048 + tid * 8);
    }
    __syncthreads();

#pragma unroll
    for (int ksub = 0; ksub < 2; ksub++) {
      const int cc = (ksub * 4 + quad) ^ rk;
      bf16x8 af[4], bfr[4];
#pragma unroll
      for (int i = 0; i < 4; i++)
        af[i] = *(const bf16x8*)(As + (wm + i * 16 + ln) * 64 + cc * 8);
#pragma unroll
      for (int j = 0; j < 4; j++)
        bfr[j] = *(const bf16x8*)(Bs + (wn + j * 16 + ln) * 64 + cc * 8);
#pragma unroll
      for (int i = 0; i < 4; i++)
#pragma unroll
        for (int j = 0; j < 4; j++)
          acc[i][j] = __builtin_amdgcn_mfma_f32_16x16x32_bf16(af[i], bfr[j], acc[i][j], 0, 0, 0);
    }
    __syncthreads();
  }

  // epilogue: C/D layout col = lane&15, row = quad*4 + reg (m89-verified)
  const int n0g = bx * 128;
#pragma unroll
  for (int i = 0; i < 4; i++) {
#pragma unroll
    for (int j = 0; j < 4; j++) {
#pragma unroll
      for (int r = 0; r < 4; r++) {
        const int lrow = wm + i * 16 + quad * 4 + r;
        const int lcol = wn + j * 16 + ln;
        const long gm  = m0 + lrow;
        const int  gn  = n0g + lcol;
        float x = acc[i][j][r];
        if (MODE == 5) {
          __hip_atomic_fetch_add(&((float*)Cg)[(long)bz * sC + gm * (long)N + gn],
                                 x, __ATOMIC_RELAXED, __HIP_MEMORY_SCOPE_AGENT);
        } else if (MODE == 7) {
          ((__bf16*)Cg)[gm * (long)N + gn] = f2bf(x);
        } else if (MODE == 8) {
          x = x * zvec[gm] + bias[gn];
          ((float*)Cg)[gm * (long)N + gn] = x + resid[gm * (long)N + gn];
        }
      }
    }
  }
}

// ---------------------------------------------------------------------------
// Mega projection GEMM: 3 heads over shared structure, grid (24,128).
//   head 0 (bx 0..7):   k_phi = phi(c@Wk + bk)   -> kphiT [b][D][S] + ksum
//   head 1 (bx 8..15):  v''   = c@Wvo + bvo      -> vT2   [b][D][S]
//   head 2 (bx 16..23): q_phi = phi(x@Wq + bq)   -> qphi  [B*S][D] row-major
// Wcat = [WkT | WvoT | WqT] (3072 x 1024 bf16).
// ---------------------------------------------------------------------------
__global__ __launch_bounds__(256)
void proj_gemm(const __bf16* __restrict__ xbf, const __bf16* __restrict__ cbf,
               const __bf16* __restrict__ Wcat,
               __bf16* __restrict__ kphiT, __bf16* __restrict__ vT2,
               __bf16* __restrict__ qphi,
               const float* __restrict__ bk, const float* __restrict__ bvo,
               const float* __restrict__ bq, float* __restrict__ ksum)
{
  union SMem {
    struct { __bf16 As[128 * 64]; __bf16 Bs[128 * 64]; } s;  // 32 KB
    __bf16 T[128 * 136];                                     // 34 KB (epilogue)
  };
  __shared__ SMem sm;

  int bx = blockIdx.x, by = blockIdx.y;
  {
    const int gx = gridDim.x, gy = gridDim.y;   // 24 x 128
    const int f = by * gx + bx;
    const int j = f & 7;
    const int u = f >> 3;
    bx = u % gx;
    by = j * (gy >> 3) + u / gx;
  }
  const int head = bx >> 3;          // 0=k, 1=v'', 2=q
  const int bxl  = bx & 7;

  const int tid = threadIdx.x;
  const long m0 = (long)by * 128;
  const __bf16* A = (head == 2 ? xbf : cbf) + m0 * DD;
  const __bf16* B = Wcat + (long)bx * 128 * DD;

  const int srow = tid >> 3;
  const int gcc8 = ((tid & 7) ^ (srow & 7)) * 8;

  const int lane = tid & 63;
  const int wave = tid >> 6;
  const int wm   = (wave >> 1) * 64;
  const int wn   = (wave & 1) * 64;
  const int ln   = lane & 15;
  const int quad = lane >> 4;
  const int rk   = ln & 7;

  f32x4 acc[4][4];
  const f32x4 zero = {0.f, 0.f, 0.f, 0.f};
#pragma unroll
  for (int i = 0; i < 4; i++)
#pragma unroll
    for (int j = 0; j < 4; j++) acc[i][j] = zero;

  for (int k0 = 0; k0 < DD; k0 += 64) {
#pragma unroll
    for (int p = 0; p < 4; p++) {
      async_load16(A + (long)(p * 32 + srow) * DD + k0 + gcc8, sm.s.As + p * 2048 + tid * 8);
      async_load16(B + (long)(p * 32 + srow) * DD + k0 + gcc8, sm.s.Bs + p * 2048 + tid * 8);
    }
    __syncthreads();

#pragma unroll
    for (int ksub = 0; ksub < 2; ksub++) {
      const int cc = (ksub * 4 + quad) ^ rk;
      bf16x8 af[4], bfr[4];
#pragma unroll
      for (int i = 0; i < 4; i++)
        af[i] = *(const bf16x8*)(sm.s.As + (wm + i * 16 + ln) * 64 + cc * 8);
#pragma unroll
      for (int j = 0; j < 4; j++)
        bfr[j] = *(const bf16x8*)(sm.s.Bs + (wn + j * 16 + ln) * 64 + cc * 8);
#pragma unroll
      for (int i = 0; i < 4; i++)
#pragma unroll
        for (int j = 0; j < 4; j++)
          acc[i][j] = __builtin_amdgcn_mfma_f32_16x16x32_bf16(af[i], bfr[j], acc[i][j], 0, 0, 0);
    }
    __syncthreads();
  }

  const int nb = bxl * 128;
  const int b  = (int)(m0 >> 12);

  if (head == 2) {
    // q_phi: row-major store
#pragma unroll
    for (int i = 0; i < 4; i++)
#pragma unroll
      for (int j = 0; j < 4; j++)
#pragma unroll
        for (int r = 0; r < 4; r++) {
          const long gm = m0 + wm + i * 16 + quad * 4 + r;
          const int  gn = nb + wn + j * 16 + ln;
          float x = acc[i][j][r] + bq[gn];
          x = (x > 0.f) ? (x + 1.f) : __expf(x);
          qphi[gm * DD + gn] = f2bf(x);
        }
    return;
  }

  // heads 0/1: transposed store via LDS; head 0 also accumulates ksum
  const bool isK = (head == 0);
  const float* bb = isK ? bk : bvo;
  float kpart[4] = {0.f, 0.f, 0.f, 0.f};
#pragma unroll
  for (int i = 0; i < 4; i++)
#pragma unroll
    for (int j = 0; j < 4; j++)
#pragma unroll
      for (int r = 0; r < 4; r++) {
        const int s_loc = wm + i * 16 + quad * 4 + r;
        const int n_loc = wn + j * 16 + ln;
        float x = acc[i][j][r] + bb[nb + n_loc];
        if (isK) { x = (x > 0.f) ? (x + 1.f) : __expf(x); kpart[j] += x; }
        sm.T[n_loc * 136 + s_loc] = f2bf(x);
      }
  if (isK) {
#pragma unroll
    for (int j = 0; j < 4; j++) {
      float s = kpart[j];
      s += __shfl_xor(s, 16);      // reduce over quad (s-dimension)
      s += __shfl_xor(s, 32);
      if (quad == 0)
        __hip_atomic_fetch_add(&ksum[(long)b * DD + nb + wn + j * 16 + ln],
                               s, __ATOMIC_RELAXED, __HIP_MEMORY_SCOPE_AGENT);
    }
  }
  __syncthreads();
  const long s_in = m0 & 4095;
  __bf16* dst = (isK ? kphiT : vT2) + (long)b * DD * SS;
#pragma unroll
  for (int pass = 0; pass < 8; pass++) {
    const int row = (tid >> 4) + pass * 16;  // d within tile
    const int c   = (tid & 15) * 8;          // s chunk
    bf16x8 vv = *(const bf16x8*)(sm.T + row * 136 + c);
    *(bf16x8*)&dst[(long)(nb + row) * SS + s_in + c] = vv;
  }
}

// ---------------------------------------------------------------------------
__global__ __launch_bounds__(256)
void cvt2_f32_bf16(const float* __restrict__ x0, const float* __restrict__ x1,
                   __bf16* __restrict__ y0, __bf16* __restrict__ y1, long n)
{
  const float* x = blockIdx.z ? x1 : x0;
  __bf16*      y = blockIdx.z ? y1 : y0;
  long i = ((long)blockIdx.x * 256 + threadIdx.x) * 4;
  if (i < n) {
    float4 v = *(const float4*)(x + i);
    bf16x4 o;
    o[0] = f2bf(v.x); o[1] = f2bf(v.y); o[2] = f2bf(v.z); o[3] = f2bf(v.w);
    *(bf16x4*)(y + i) = o;
  }
}

__global__ __launch_bounds__(256)
void cvt_f32_bf16(const float* __restrict__ x, __bf16* __restrict__ y, long n)
{
  long i = ((long)blockIdx.x * 256 + threadIdx.x) * 4;
  if (i < n) {
    float4 v = *(const float4*)(x + i);
    bf16x4 o;
    o[0] = f2bf(v.x); o[1] = f2bf(v.y); o[2] = f2bf(v.z); o[3] = f2bf(v.w);
    *(bf16x4*)(y + i) = o;
  }
}

// ---------------------------------------------------------------------------
// Weight transpose + convert: W fp32 [D][D] -> WT bf16 [D][D]; 4 weights via z
// ---------------------------------------------------------------------------
__global__ __launch_bounds__(256)
void wtrans(const float* W0, const float* W1, const float* W2, const float* W3,
            __bf16* O0, __bf16* O1, __bf16* O2, __bf16* O3, int Dd)
{
  __shared__ __bf16 t[64][72];
  const float* W = (blockIdx.z == 0) ? W0 : (blockIdx.z == 1) ? W1 : (blockIdx.z == 2) ? W2 : W3;
  __bf16*      O = (blockIdx.z == 0) ? O0 : (blockIdx.z == 1) ? O1 : (blockIdx.z == 2) ? O2 : O3;
  const int r0 = blockIdx.y * 64, c0 = blockIdx.x * 64;
  const int tid = threadIdx.x;
  const int lr4 = tid >> 4, lc4 = (tid & 15) * 4;
#pragma unroll
  for (int it = 0; it < 4; it++) {
    const int row = lr4 + it * 16;
    float4 v = *(const float4*)&W[(long)(r0 + row) * Dd + c0 + lc4];
    t[row][lc4 + 0] = f2bf(v.x);
    t[row][lc4 + 1] = f2bf(v.y);
    t[row][lc4 + 2] = f2bf(v.z);
    t[row][lc4 + 3] = f2bf(v.w);
  }
  __syncthreads();
  const int lr8 = tid >> 3, lc8 = (tid & 7) * 8;
#pragma unroll
  for (int it = 0; it < 2; it++) {
    const int orow = lr8 + it * 32;
    bf16x8 vb;
#pragma unroll
    for (int j = 0; j < 8; j++) vb[j] = t[lc8 + j][orow];
    *(bf16x8*)&O[(long)(c0 + orow) * Dd + r0 + lc8] = vb;
  }
}

// ---------------------------------------------------------------------------
// bvo[f] = sum_e bv[e] * Wo[e][f]   (fp32, tiny)
// ---------------------------------------------------------------------------
__global__ __launch_bounds__(256)
void bvo_k(const float* __restrict__ bv, const float* __restrict__ Wo,
           float* __restrict__ bvo)
{
  const int f = blockIdx.x * 256 + threadIdx.x;
  float s = 0.f;
  for (int e = 0; e < DD; e++) s += bv[e] * Wo[(long)e * DD + f];
  bvo[f] = s;
}

// ---------------------------------------------------------------------------
// z[b*S+s] = 1 / (q_phi[row] . k_sum[b] + 1e-6)
// ---------------------------------------------------------------------------
__global__ __launch_bounds__(256)
void zden_k(const __bf16* __restrict__ qphi, const float* __restrict__ ksum,
            float* __restrict__ z, int Dd, int S)
{
  const long row = blockIdx.x;
  const int  b   = (int)(row / S);
  const __bf16* q = qphi + row * (long)Dd;
  const float* ks = ksum + (long)b * Dd;
  const int tid = threadIdx.x;
  const int i = tid * 4;                      // Dd = 1024 = 256*4 exactly
  bf16x4 qv = *(const bf16x4*)&q[i];
  float4 kv4 = *(const float4*)&ks[i];
  float s = (float)qv[0] * kv4.x + (float)qv[1] * kv4.y +
            (float)qv[2] * kv4.z + (float)qv[3] * kv4.w;
  __shared__ float red[256];
  red[tid] = s; __syncthreads();
  for (int off = 128; off > 0; off >>= 1) {
    if (tid < off) red[tid] += red[tid + off];
    __syncthreads();
  }
  if (tid == 0) z[row] = 1.f / (red[0] + 1e-6f);
}

// ---------------------------------------------------------------------------
extern "C" void kernel_launch(void* const* d_in, const int* in_sizes, int n_in,
                              void* d_out, int out_size, void* d_ws, size_t ws_size,
                              hipStream_t stream)
{
  const float* inputs  = (const float*)d_in[0];
  const float* context = (const float*)d_in[1];
  const float* Wq = (const float*)d_in[2];
  const float* bq = (const float*)d_in[3];
  const float* Wk = (const float*)d_in[4];
  const float* bk = (const float*)d_in[5];
  const float* Wv = (const float*)d_in[6];
  const float* bv = (const float*)d_in[7];
  const float* Wo = (const float*)d_in[8];
  const float* bo = (const float*)d_in[9];
  float* out = (float*)d_out;

  const int Bn = 4;
  const long NSD = (long)Bn * SS * DD;         // 16,777,216
  const long MB = 1L << 20;

  char* ws = (char*)d_ws;
  __bf16* xbf   = (__bf16*)(ws + 0 * MB);      // 32 MB
  __bf16* cbf   = (__bf16*)(ws + 32 * MB);     // 32 MB
  __bf16* qphi  = (__bf16*)(ws + 64 * MB);     // 32 MB   [B*S][D]
  __bf16* kphiT = (__bf16*)(ws + 96 * MB);     // 32 MB   [b][D][S]
  __bf16* vT2   = (__bf16*)(ws + 128 * MB);    // 32 MB   [b][F][S]  (v@Wo)^T
  float*  M2f   = (float*)(ws + 160 * MB);     // 16 MB   [b][F][D] fp32 (atomics)
  float*  ksum  = (float*)(ws + 176 * MB);     // 16 KB   (contiguous w/ M2f for memset)
  float*  zbuf  = (float*)(ws + 177 * MB);     // 64 KB
  __bf16* M2bf  = (__bf16*)(ws + 178 * MB);    // 8 MB    [b][F][D]
  __bf16* Wcat  = (__bf16*)(ws + 192 * MB);    // 6 MB: [WkT | WvoT | WqT]
  __bf16* WkT   = Wcat;
  __bf16* WvoT  = Wcat + (long)DD * DD;
  __bf16* WqT   = Wcat + 2L * DD * DD;
  __bf16* WvT   = (__bf16*)(ws + 198 * MB);    // 2 MB
  __bf16* WoT   = (__bf16*)(ws + 200 * MB);    // 2 MB
  float*  bvo   = (float*)(ws + 202 * MB);     // 4 KB

  // 1) zero M2f + ksum (contiguous), converts, weight transposes
  hipMemsetAsync(M2f, 0, (size_t)Bn * DD * DD * sizeof(float) + (size_t)Bn * DD * sizeof(float), stream);
  cvt2_f32_bf16<<<dim3(16384, 1, 2), 256, 0, stream>>>(inputs, context, xbf, cbf, NSD);
  wtrans<<<dim3(16, 16, 4), 256, 0, stream>>>(Wq, Wk, Wv, Wo, WqT, WkT, WvT, WoT, DD);
  bvo_k<<<4, 256, 0, stream>>>(bv, Wo, bvo);

  // 2) WvoT[f][d] = sum_e WoT[f][e] * WvT[d][e]  == (Wv@Wo)^T   (tiny)
  gemm_bt<7><<<dim3(8, 8, 1), 256, 0, stream>>>(WoT, WvT, WvoT,
      DD, DD, 0, 0, 0, nullptr, nullptr, nullptr);

  // 3) mega projection: k_phi (T) + ksum, v'' (T), q_phi (row-major)
  proj_gemm<<<dim3(24, 128, 1), 256, 0, stream>>>(xbf, cbf, Wcat,
      kphiT, vT2, qphi, bk, bvo, bq, ksum);

  // 4) z
  zden_k<<<16384, 256, 0, stream>>>(qphi, ksum, zbuf, DD, SS);

  // 5) M2T[b][f][d] = sum_s vT2[b][f][s] * kphiT[b][d][s], split-K(4) atomics
  gemm_bt<5><<<dim3(8, 8, 16), 256, 0, stream>>>(vT2, kphiT, M2f,
      DD, SS, (long)DD * SS, (long)DD * SS, (long)DD * DD,
      nullptr, nullptr, nullptr);
  cvt_f32_bf16<<<4096, 256, 0, stream>>>(M2f, M2bf, (long)Bn * DD * DD);

  // 6) out[s][f] = z[s]*(sum_d qphi[s][d]*M2T[b][f][d]) + bo[f] + inputs[s][f]
  gemm_bt<8><<<dim3(8, 128, 1), 256, 0, stream>>>(qphi, M2bf, out,
      DD, DD, 0, (long)DD * DD, 0, bo, zbuf, inputs);
}